// Round 8
// baseline (447.850 us; speedup 1.0000x reference)
//
#include <hip/hip_runtime.h>
#include <math.h>

#define BATCH 4
#define CH 512
#define NTOK 4096
#define NGRP 32
#define CPG 16
#define GN_EPS 1e-6f

typedef __attribute__((ext_vector_type(8))) short short8;
typedef __attribute__((ext_vector_type(4))) short short4v;
typedef __attribute__((ext_vector_type(4))) float floatx4;

__device__ __forceinline__ short f2bf(float f) {
    unsigned u = __float_as_uint(f);
    u += 0x7fffu + ((u >> 16) & 1u);
    return (short)(u >> 16);
}
__device__ __forceinline__ float bf2f(short s) {
    return __uint_as_float(((unsigned)(unsigned short)s) << 16);
}

__device__ __forceinline__ void load_lds16(const void* g, void* l) {
    __builtin_amdgcn_global_load_lds(
        (const __attribute__((address_space(1))) void*)g,
        (__attribute__((address_space(3))) void*)l,
        16, 0, 0);
}

// ---------------------------------------------------------------------------
// GroupNorm stats, partial: grid (4 parts, 128 bg). partials[bg*4+p]=(sum,ssq)
// ---------------------------------------------------------------------------
__global__ __launch_bounds__(256)
void gn_stats_partial(const float* __restrict__ x, float2* __restrict__ partials)
{
    const int part = blockIdx.x;
    const int bg = blockIdx.y;
    const float4* xp = (const float4*)(x + (size_t)bg * CPG * NTOK) + part * 4096;
    float s = 0.f, ss = 0.f;
    for (int i = threadIdx.x; i < 4096; i += 256) {
        float4 v = xp[i];
        s  += v.x + v.y + v.z + v.w;
        ss += v.x * v.x + v.y * v.y + v.z * v.z + v.w * v.w;
    }
    __shared__ float r0[4], r1[4];
    for (int off = 32; off >= 1; off >>= 1) {
        s  += __shfl_down(s, off);
        ss += __shfl_down(ss, off);
    }
    const int lane = threadIdx.x & 63, wave = threadIdx.x >> 6;
    if (lane == 0) { r0[wave] = s; r1[wave] = ss; }
    __syncthreads();
    if (threadIdx.x == 0) {
        float2 o;
        o.x = r0[0] + r0[1] + r0[2] + r0[3];
        o.y = r1[0] + r1[1] + r1[2] + r1[3];
        partials[bg * 4 + part] = o;
    }
}

// ---------------------------------------------------------------------------
// GroupNorm apply + transpose + bf16. x[b][c][n] -> hnT[b][n][c] bf16.
// ---------------------------------------------------------------------------
__global__ __launch_bounds__(256)
void gn_apply_t(const float* __restrict__ x, const float* __restrict__ gamma,
                const float* __restrict__ beta, const float2* __restrict__ partials,
                short* __restrict__ hnT)
{
    const int b = blockIdx.z;
    const int c0 = blockIdx.y * 32;
    const int n0 = blockIdx.x * 32;
    __shared__ short tile[32][33];
    const int t = threadIdx.x;

    const int cl = t >> 3;
    const int nl = (t & 7) * 4;
    const int c = c0 + cl;
    const int bg = b * NGRP + c / CPG;
    float2 p0 = partials[bg * 4 + 0], p1 = partials[bg * 4 + 1];
    float2 p2 = partials[bg * 4 + 2], p3 = partials[bg * 4 + 3];
    const float inv = 1.f / (float)(CPG * NTOK);
    const float mean = (p0.x + p1.x + p2.x + p3.x) * inv;
    const float var = (p0.y + p1.y + p2.y + p3.y) * inv - mean * mean;
    const float rstd = rsqrtf(var + GN_EPS);
    const float ga = gamma[c] * rstd, be = beta[c] - mean * ga;
    const float4 v = *(const float4*)(x + ((size_t)b * CH + c) * NTOK + n0 + nl);
    tile[cl][nl + 0] = f2bf(v.x * ga + be);
    tile[cl][nl + 1] = f2bf(v.y * ga + be);
    tile[cl][nl + 2] = f2bf(v.z * ga + be);
    tile[cl][nl + 3] = f2bf(v.w * ga + be);
    __syncthreads();

    const int nw = t >> 3;
    const int cw = (t & 7) * 4;
    short4v o;
    o.x = tile[cw + 0][nw];
    o.y = tile[cw + 1][nw];
    o.z = tile[cw + 2][nw];
    o.w = tile[cw + 3][nw];
    *(short4v*)(hnT + ((size_t)b * NTOK + n0 + nw) * CH + c0 + cw) = o;
}

// ---------------------------------------------------------------------------
// Weight casts. Grid (256, 4).
// ---------------------------------------------------------------------------
__global__ __launch_bounds__(256)
void cast_weights(const float* q, const float* k, const float* v, const float* p,
                  short* wqk, short* wv, short* wp)
{
    const float* w; short* o;
    switch (blockIdx.y) {
        case 0: w = q; o = wqk; break;
        case 1: w = k; o = wqk + CH * CH; break;
        case 2: w = v; o = wv; break;
        default: w = p; o = wp; break;
    }
    const int i = blockIdx.x * 256 + threadIdx.x;
    const float4 vv = ((const float4*)w)[i];
    short4v s; s.x = f2bf(vv.x); s.y = f2bf(vv.y); s.z = f2bf(vv.z); s.w = f2bf(vv.w);
    ((short4v*)o)[i] = s;
}

// concat bias + zero the rowsum accumulator. Grid 68 blocks.
__global__ __launch_bounds__(256)
void concat_bias_zero_rs(const float* q_b, const float* k_b, float* qkb, float* RS)
{
    const int i = blockIdx.x * 256 + threadIdx.x;
    if (i < 1024) qkb[i] = (i < CH) ? q_b[i] : k_b[i - CH];
    const int r = i - 1024;                 // 68*256-1024 = 16384
    if (r >= 0) RS[r] = 0.f;
}

// ---------------------------------------------------------------------------
// bf16 MFMA GEMM (TN): C[m][n] = scale*sum_k A[m][k]*B[n][k] (+bias)(+res)
// MODE: 0 = fp32 out (direct store), 1 = bf16 out, 2 = bf16 exp(out)+row-atomics
// MODE>=1 uses LDS-staged coalesced epilogue (16B/lane dwordx4 stores).
// SPLITK: z encodes (split=z>>2, batch=z&3); k-range offset split*K.
// ---------------------------------------------------------------------------
template<int BM, int BN, int BK, int WAVES_M, int MODE, int BIAS_M,
         int BIAS_N, int ADD_RES, int SWAP_XY, int SPLITK>
__global__ __launch_bounds__(256)
void mfma_gemm(const short* __restrict__ A, const short* __restrict__ B,
               void* __restrict__ Cv, const float* __restrict__ bias,
               const float* __restrict__ res, float* __restrict__ rsum,
               float scale, int K, int lda, int ldb, int ldc,
               long sA, long sB, long sC)
{
    constexpr int WAVES_N = 4 / WAVES_M;
    constexpr int WM = BM / WAVES_M;
    constexpr int WN = BN / WAVES_N;
    constexpr int MT = WM / 16;
    constexpr int NT = WN / 16;
    constexpr int KS = BK / 32;
    constexpr int TPR = BK / 8;
    constexpr int RPI = 256 / TPR;
    constexpr int CPITCH = BN + 8;
    constexpr int STAGE = BM * BK + BN * BK;
    constexpr int EPI = (MODE >= 1) ? BM * CPITCH : 0;
    constexpr int LDSE = STAGE > EPI ? STAGE : EPI;

    __shared__ __align__(16) short lds[LDSE];
    short* As = lds;
    short* Bs = lds + BM * BK;

    const int z = blockIdx.z;
    const int zb = SPLITK ? (z & 3) : z;
    const int koff = SPLITK ? (z >> 2) * K : 0;
    const short* Ap = A + (size_t)zb * sA + koff;
    const short* Bp = B + (size_t)zb * sB + koff;

    const int m0 = (SWAP_XY ? blockIdx.x : blockIdx.y) * BM;
    const int n0 = (SWAP_XY ? blockIdx.y : blockIdx.x) * BN;
    const int t = threadIdx.x;
    const int w = t >> 6, lane = t & 63;
    const int wm = (w % WAVES_M) * WM;
    const int wn = (w / WAVES_M) * WN;
    const int lr = lane & 15, lq = lane >> 4;

    floatx4 acc[MT][NT];
#pragma unroll
    for (int mt = 0; mt < MT; mt++)
#pragma unroll
        for (int nt = 0; nt < NT; nt++)
            acc[mt][nt] = (floatx4){0.f, 0.f, 0.f, 0.f};

    const int rA = t / TPR;
    const int kA = (t % TPR) * 8;

    for (int k0 = 0; k0 < K; k0 += BK) {
#pragma unroll
        for (int r = 0; r < BM; r += RPI)
            load_lds16(Ap + (size_t)(m0 + r + rA) * lda + k0 + kA,
                       &As[(r + rA) * BK + kA]);
#pragma unroll
        for (int r = 0; r < BN; r += RPI)
            load_lds16(Bp + (size_t)(n0 + r + rA) * ldb + k0 + kA,
                       &Bs[(r + rA) * BK + kA]);
        __syncthreads();

#pragma unroll
        for (int ks = 0; ks < KS; ks++) {
            short8 af[MT], bfr[NT];
#pragma unroll
            for (int mt = 0; mt < MT; mt++)
                af[mt] = *(const short8*)&As[(wm + mt * 16 + lr) * BK + ks * 32 + lq * 8];
#pragma unroll
            for (int nt = 0; nt < NT; nt++)
                bfr[nt] = *(const short8*)&Bs[(wn + nt * 16 + lr) * BK + ks * 32 + lq * 8];
#pragma unroll
            for (int mt = 0; mt < MT; mt++)
#pragma unroll
                for (int nt = 0; nt < NT; nt++)
                    acc[mt][nt] = __builtin_amdgcn_mfma_f32_16x16x32_bf16(
                        af[mt], bfr[nt], acc[mt][nt], 0, 0, 0);
        }
        __syncthreads();
    }

    // C/D: col = lane&15, row = (lane>>4)*4 + r  [m89-verified]
    const size_t cz = (size_t)z * sC;
    if (MODE >= 1) {
        short* Cs = lds;
#pragma unroll
        for (int mt = 0; mt < MT; mt++) {
#pragma unroll
            for (int r = 0; r < 4; r++) {
                const int rowLoc = wm + mt * 16 + lq * 4 + r;
                const float bm = BIAS_M ? bias[m0 + rowLoc] : 0.f;
                float rsum_l = 0.f;
#pragma unroll
                for (int nt = 0; nt < NT; nt++) {
                    const int colLoc = wn + nt * 16 + lr;
                    float v = acc[mt][nt][r] * scale + bm;
                    if (BIAS_N) v += bias[n0 + colLoc];
                    if (MODE == 2) { v = __expf(v); rsum_l += v; }
                    Cs[rowLoc * CPITCH + colLoc] = f2bf(v);
                }
                if (MODE == 2) {
                    rsum_l += __shfl_xor(rsum_l, 1);
                    rsum_l += __shfl_xor(rsum_l, 2);
                    rsum_l += __shfl_xor(rsum_l, 4);
                    rsum_l += __shfl_xor(rsum_l, 8);
                    if (lr == 0)
                        atomicAdd(&rsum[(size_t)z * NTOK + m0 + rowLoc], rsum_l);
                }
            }
        }
        __syncthreads();
        short* Cout = (short*)Cv;
        constexpr int VPR = BN / 8;
        constexpr int TOT = BM * VPR;
#pragma unroll
        for (int i = 0; i < TOT / 256; i++) {
            const int idx = i * 256 + t;
            const int row = idx / VPR;
            const int cv = idx % VPR;
            short8 val = *(const short8*)&Cs[row * CPITCH + cv * 8];
            *(short8*)&Cout[cz + (size_t)(m0 + row) * ldc + n0 + cv * 8] = val;
        }
    } else {
#pragma unroll
        for (int mt = 0; mt < MT; mt++) {
#pragma unroll
            for (int r = 0; r < 4; r++) {
                const int row = m0 + wm + mt * 16 + lq * 4 + r;
                const float bm = BIAS_M ? bias[row] : 0.f;
#pragma unroll
                for (int nt = 0; nt < NT; nt++) {
                    const int col = n0 + wn + nt * 16 + lr;
                    float v = acc[mt][nt][r] * scale + bm;
                    if (BIAS_N) v += bias[col];
                    const size_t idx = cz + (size_t)row * ldc + col;
                    if (ADD_RES) v += res[idx];
                    ((float*)Cv)[idx] = v;
                }
            }
        }
    }
}

// ---------------------------------------------------------------------------
// Split-K reduce: O[row][c] = (P0 + P1) / RS[row].  short8 granularity.
// ---------------------------------------------------------------------------
__global__ __launch_bounds__(256)
void pv_reduce(const short* __restrict__ P0, const short* __restrict__ P1,
               const float* __restrict__ RS, short* __restrict__ O)
{
    const int idx = blockIdx.x * 256 + threadIdx.x;   // short8 units
    const int row = idx >> 6;                         // 64 units per 512-col row
    const float inv = 1.f / RS[row];
    short8 a = ((const short8*)P0)[idx];
    short8 b = ((const short8*)P1)[idx];
    short8 o;
#pragma unroll
    for (int e = 0; e < 8; e++)
        o[e] = f2bf((bf2f(a[e]) + bf2f(b[e])) * inv);
    ((short8*)O)[idx] = o;
}

// ---------------------------------------------------------------------------
// Launch
// ---------------------------------------------------------------------------
extern "C" void kernel_launch(void* const* d_in, const int* in_sizes, int n_in,
                              void* d_out, int out_size, void* d_ws, size_t ws_size,
                              hipStream_t stream)
{
    (void)in_sizes; (void)n_in; (void)out_size; (void)ws_size;
    const float* x      = (const float*)d_in[0];
    const float* norm_w = (const float*)d_in[1];
    const float* norm_b = (const float*)d_in[2];
    const float* q_w    = (const float*)d_in[3];
    const float* q_b    = (const float*)d_in[4];
    const float* k_w    = (const float*)d_in[5];
    const float* k_b    = (const float*)d_in[6];
    const float* v_w    = (const float*)d_in[7];
    const float* v_b    = (const float*)d_in[8];
    const float* p_w    = (const float*)d_in[9];
    const float* p_b    = (const float*)d_in[10];

    const size_t CN2 = (size_t)NTOK * CH;

    short* hnT = (short*)d_ws;                        // [B][N][C]
    short* QK  = hnT + (size_t)BATCH * CN2;           // [B][N][1024]; later PV partials [2][B][N][C]
    short* V   = QK  + (size_t)BATCH * NTOK * 1024;   // [B][C][N]
    short* O   = V   + (size_t)BATCH * CN2;           // [B][N][C]
    short* wqk = O   + (size_t)BATCH * CN2;           // [1024][512]
    short* wv  = wqk + (size_t)1024 * CH;
    short* wp  = wv  + (size_t)CH * CH;
    short* S   = wp  + (size_t)CH * CH;               // E = exp(scores) [B][N][N] bf16
    float* qkb = (float*)(S + (size_t)BATCH * NTOK * NTOK);   // [1024]
    float2* partials = (float2*)(qkb + 1024);                 // [512]
    float* RS = (float*)(partials + 512);                     // [B][N] rowsums

    gn_stats_partial<<<dim3(4, BATCH * NGRP), 256, 0, stream>>>(x, partials);
    cast_weights<<<dim3(256, 4), 256, 0, stream>>>(q_w, k_w, v_w, p_w, wqk, wv, wp);
    concat_bias_zero_rs<<<68, 256, 0, stream>>>(q_b, k_b, qkb, RS);
    gn_apply_t<<<dim3(NTOK / 32, CH / 32, BATCH), 256, 0, stream>>>(
        x, norm_w, norm_b, partials, hnT);

    // Fused Q+K conv
    mfma_gemm<128, 128, 64, 2, 1, 0, 1, 0, 0, 0><<<dim3(1024 / 128, NTOK / 128, BATCH), 256, 0, stream>>>(
        hnT, wqk, QK, qkb, nullptr, nullptr, 1.f, CH, CH, CH, 1024,
        (long)CN2, 0, (long)NTOK * 1024);
    // V conv
    mfma_gemm<128, 128, 64, 2, 1, 1, 0, 0, 0, 0><<<dim3(NTOK / 128, CH / 128, BATCH), 256, 0, stream>>>(
        wv, hnT, V, v_b, nullptr, nullptr, 1.f, CH, CH, CH, NTOK,
        0, (long)CN2, (long)CN2);

    const float scale = 1.0f / sqrtf((float)CH);
    // scores -> E = exp(s*scale) bf16 + rowsum atomics into RS
    mfma_gemm<128, 128, 64, 2, 2, 0, 0, 0, 0, 0><<<dim3(NTOK / 128, NTOK / 128, BATCH), 256, 0, stream>>>(
        QK, QK + CH, S, nullptr, nullptr, RS, scale, CH, 1024, 1024, NTOK,
        (long)NTOK * 1024, (long)NTOK * 1024, (long)NTOK * NTOK);
    // PV split-K=2, single dispatch (z = split*4 + batch), bf16 partials over QK
    mfma_gemm<128, 64, 64, 2, 1, 0, 0, 0, 1, 1><<<dim3(NTOK / 128, CH / 64, 8), 256, 0, stream>>>(
        S, V, QK, nullptr, nullptr, nullptr, 1.f, NTOK / 2, NTOK, NTOK, CH,
        (long)NTOK * NTOK, (long)CN2, (long)CN2);
    // combine partials, divide by rowsum -> O bf16
    pv_reduce<<<(BATCH * NTOK * CH / 8) / 256, 256, 0, stream>>>(
        QK, QK + (size_t)BATCH * CN2, RS, O);

    // proj + bias + residual -> out fp32 [b][c][n]
    mfma_gemm<128, 128, 64, 2, 0, 1, 0, 1, 0, 0><<<dim3(NTOK / 128, CH / 128, BATCH), 256, 0, stream>>>(
        wp, O, d_out, p_b, x, nullptr, 1.f, CH, CH, CH, NTOK,
        0, (long)CN2, (long)CN2);
}

// Round 9
// 430.806 us; speedup vs baseline: 1.0396x; 1.0396x over previous
//
#include <hip/hip_runtime.h>
#include <math.h>

#define BATCH 4
#define CH 512
#define NTOK 4096
#define NGRP 32
#define CPG 16
#define GN_EPS 1e-6f

typedef __attribute__((ext_vector_type(8))) short short8;
typedef __attribute__((ext_vector_type(4))) short short4v;
typedef __attribute__((ext_vector_type(4))) float floatx4;

__device__ __forceinline__ short f2bf(float f) {
    unsigned u = __float_as_uint(f);
    u += 0x7fffu + ((u >> 16) & 1u);
    return (short)(u >> 16);
}
__device__ __forceinline__ float bf2f(short s) {
    return __uint_as_float(((unsigned)(unsigned short)s) << 16);
}

__device__ __forceinline__ void load_lds16(const void* g, void* l) {
    __builtin_amdgcn_global_load_lds(
        (const __attribute__((address_space(1))) void*)g,
        (__attribute__((address_space(3))) void*)l,
        16, 0, 0);
}

// ---------------------------------------------------------------------------
// GroupNorm stats, partial: grid (4 parts, 128 bg). partials[bg*4+p]=(sum,ssq)
// ---------------------------------------------------------------------------
__global__ __launch_bounds__(256)
void gn_stats_partial(const float* __restrict__ x, float2* __restrict__ partials)
{
    const int part = blockIdx.x;
    const int bg = blockIdx.y;
    const float4* xp = (const float4*)(x + (size_t)bg * CPG * NTOK) + part * 4096;
    float s = 0.f, ss = 0.f;
    for (int i = threadIdx.x; i < 4096; i += 256) {
        float4 v = xp[i];
        s  += v.x + v.y + v.z + v.w;
        ss += v.x * v.x + v.y * v.y + v.z * v.z + v.w * v.w;
    }
    __shared__ float r0[4], r1[4];
    for (int off = 32; off >= 1; off >>= 1) {
        s  += __shfl_down(s, off);
        ss += __shfl_down(ss, off);
    }
    const int lane = threadIdx.x & 63, wave = threadIdx.x >> 6;
    if (lane == 0) { r0[wave] = s; r1[wave] = ss; }
    __syncthreads();
    if (threadIdx.x == 0) {
        float2 o;
        o.x = r0[0] + r0[1] + r0[2] + r0[3];
        o.y = r1[0] + r1[1] + r1[2] + r1[3];
        partials[bg * 4 + part] = o;
    }
}

// ---------------------------------------------------------------------------
// GroupNorm apply + transpose + bf16. x[b][c][n] -> hnT[b][n][c] bf16.
// ---------------------------------------------------------------------------
__global__ __launch_bounds__(256)
void gn_apply_t(const float* __restrict__ x, const float* __restrict__ gamma,
                const float* __restrict__ beta, const float2* __restrict__ partials,
                short* __restrict__ hnT)
{
    const int b = blockIdx.z;
    const int c0 = blockIdx.y * 32;
    const int n0 = blockIdx.x * 32;
    __shared__ short tile[32][33];
    const int t = threadIdx.x;

    const int cl = t >> 3;
    const int nl = (t & 7) * 4;
    const int c = c0 + cl;
    const int bg = b * NGRP + c / CPG;
    float2 p0 = partials[bg * 4 + 0], p1 = partials[bg * 4 + 1];
    float2 p2 = partials[bg * 4 + 2], p3 = partials[bg * 4 + 3];
    const float inv = 1.f / (float)(CPG * NTOK);
    const float mean = (p0.x + p1.x + p2.x + p3.x) * inv;
    const float var = (p0.y + p1.y + p2.y + p3.y) * inv - mean * mean;
    const float rstd = rsqrtf(var + GN_EPS);
    const float ga = gamma[c] * rstd, be = beta[c] - mean * ga;
    const float4 v = *(const float4*)(x + ((size_t)b * CH + c) * NTOK + n0 + nl);
    tile[cl][nl + 0] = f2bf(v.x * ga + be);
    tile[cl][nl + 1] = f2bf(v.y * ga + be);
    tile[cl][nl + 2] = f2bf(v.z * ga + be);
    tile[cl][nl + 3] = f2bf(v.w * ga + be);
    __syncthreads();

    const int nw = t >> 3;
    const int cw = (t & 7) * 4;
    short4v o;
    o.x = tile[cw + 0][nw];
    o.y = tile[cw + 1][nw];
    o.z = tile[cw + 2][nw];
    o.w = tile[cw + 3][nw];
    *(short4v*)(hnT + ((size_t)b * NTOK + n0 + nw) * CH + c0 + cw) = o;
}

// ---------------------------------------------------------------------------
// Weight casts. Grid (256, 4).
// ---------------------------------------------------------------------------
__global__ __launch_bounds__(256)
void cast_weights(const float* q, const float* k, const float* v, const float* p,
                  short* wqk, short* wv, short* wp)
{
    const float* w; short* o;
    switch (blockIdx.y) {
        case 0: w = q; o = wqk; break;
        case 1: w = k; o = wqk + CH * CH; break;
        case 2: w = v; o = wv; break;
        default: w = p; o = wp; break;
    }
    const int i = blockIdx.x * 256 + threadIdx.x;
    const float4 vv = ((const float4*)w)[i];
    short4v s; s.x = f2bf(vv.x); s.y = f2bf(vv.y); s.z = f2bf(vv.z); s.w = f2bf(vv.w);
    ((short4v*)o)[i] = s;
}

__global__ __launch_bounds__(256)
void concat_bias(const float* q_b, const float* k_b, float* qkb)
{
    const int i = blockIdx.x * 256 + threadIdx.x;
    qkb[i] = (i < CH) ? q_b[i] : k_b[i - CH];
}

// ---------------------------------------------------------------------------
// bf16 MFMA GEMM (TN): C[m][n] = scale*sum_k A[m][k]*B[n][k] (+bias)(+res)
// MODE: 0 = fp32 out (direct store), 1 = bf16 out, 2 = bf16 exp(out)
// MODE>=1: chunked LDS-staged epilogue (64 rows at a time, coalesced stores).
// SPLITK: z encodes (split=z>>2, batch=z&3); k-range offset split*K.
// ROWSUM: ones-MFMA rowsum of A; n0==0 blocks store fp32 partials to rsum.
// ---------------------------------------------------------------------------
template<int BM, int BN, int BK, int WAVES_M, int MODE, int BIAS_M,
         int BIAS_N, int ADD_RES, int SWAP_XY, int SPLITK, int ROWSUM>
__global__ __launch_bounds__(256)
void mfma_gemm(const short* __restrict__ A, const short* __restrict__ B,
               void* __restrict__ Cv, const float* __restrict__ bias,
               const float* __restrict__ res, float* __restrict__ rsum,
               float scale, int K, int lda, int ldb, int ldc,
               long sA, long sB, long sC)
{
    constexpr int WAVES_N = 4 / WAVES_M;
    constexpr int WM = BM / WAVES_M;
    constexpr int WN = BN / WAVES_N;
    constexpr int MT = WM / 16;
    constexpr int NT = WN / 16;
    constexpr int KS = BK / 32;
    constexpr int TPR = BK / 8;
    constexpr int RPI = 256 / TPR;
    constexpr int CPITCH = BN + 8;
    constexpr int STAGE = BM * BK + BN * BK;
    constexpr int EPI = (MODE >= 1) ? 64 * CPITCH : 0;
    constexpr int LDSE = STAGE > EPI ? STAGE : EPI;

    __shared__ __align__(16) short lds[LDSE];
    short* As = lds;
    short* Bs = lds + BM * BK;

    const int z = blockIdx.z;
    const int zb = SPLITK ? (z & 3) : z;
    const int koff = SPLITK ? (z >> 2) * K : 0;
    const short* Ap = A + (size_t)zb * sA + koff;
    const short* Bp = B + (size_t)zb * sB + koff;

    const int m0 = (SWAP_XY ? blockIdx.x : blockIdx.y) * BM;
    const int n0 = (SWAP_XY ? blockIdx.y : blockIdx.x) * BN;
    const int t = threadIdx.x;
    const int w = t >> 6, lane = t & 63;
    const int wm = (w % WAVES_M) * WM;
    const int wn = (w / WAVES_M) * WN;
    const int lr = lane & 15, lq = lane >> 4;

    floatx4 acc[MT][NT];
#pragma unroll
    for (int mt = 0; mt < MT; mt++)
#pragma unroll
        for (int nt = 0; nt < NT; nt++)
            acc[mt][nt] = (floatx4){0.f, 0.f, 0.f, 0.f};

    floatx4 accr[ROWSUM ? MT : 1];
    if (ROWSUM)
#pragma unroll
        for (int mt = 0; mt < MT; mt++) accr[mt] = (floatx4){0.f, 0.f, 0.f, 0.f};
    const short kOne = (short)0x3F80;   // bf16 1.0
    const short8 ones = {kOne, kOne, kOne, kOne, kOne, kOne, kOne, kOne};

    const int rA = t / TPR;
    const int kA = (t % TPR) * 8;

    for (int k0 = 0; k0 < K; k0 += BK) {
#pragma unroll
        for (int r = 0; r < BM; r += RPI)
            load_lds16(Ap + (size_t)(m0 + r + rA) * lda + k0 + kA,
                       &As[(r + rA) * BK + kA]);
#pragma unroll
        for (int r = 0; r < BN; r += RPI)
            load_lds16(Bp + (size_t)(n0 + r + rA) * ldb + k0 + kA,
                       &Bs[(r + rA) * BK + kA]);
        __syncthreads();

#pragma unroll
        for (int ks = 0; ks < KS; ks++) {
            short8 af[MT], bfr[NT];
#pragma unroll
            for (int mt = 0; mt < MT; mt++)
                af[mt] = *(const short8*)&As[(wm + mt * 16 + lr) * BK + ks * 32 + lq * 8];
#pragma unroll
            for (int nt = 0; nt < NT; nt++)
                bfr[nt] = *(const short8*)&Bs[(wn + nt * 16 + lr) * BK + ks * 32 + lq * 8];
#pragma unroll
            for (int mt = 0; mt < MT; mt++) {
#pragma unroll
                for (int nt = 0; nt < NT; nt++)
                    acc[mt][nt] = __builtin_amdgcn_mfma_f32_16x16x32_bf16(
                        af[mt], bfr[nt], acc[mt][nt], 0, 0, 0);
                if (ROWSUM)
                    accr[mt] = __builtin_amdgcn_mfma_f32_16x16x32_bf16(
                        af[mt], ones, accr[mt], 0, 0, 0);
            }
        }
        __syncthreads();
    }

    // C/D: col = lane&15, row = (lane>>4)*4 + r  [m89-verified]
    const size_t cz = (size_t)z * sC;
    if (MODE >= 1) {
        short* Cs = lds;
        short* Cout = (short*)Cv;
        constexpr int VPR = BN / 8;
#pragma unroll
        for (int c = 0; c < BM / 64; c++) {
            if (wm == c * 64) {
#pragma unroll
                for (int mt = 0; mt < MT; mt++) {
#pragma unroll
                    for (int r = 0; r < 4; r++) {
                        const int rowLoc = wm + mt * 16 + lq * 4 + r;
                        const int rowCs = rowLoc - c * 64;
                        const float bm = BIAS_M ? bias[m0 + rowLoc] : 0.f;
#pragma unroll
                        for (int nt = 0; nt < NT; nt++) {
                            const int colLoc = wn + nt * 16 + lr;
                            float v = acc[mt][nt][r] * scale + bm;
                            if (BIAS_N) v += bias[n0 + colLoc];
                            if (MODE == 2) v = __expf(v);
                            Cs[rowCs * CPITCH + colLoc] = f2bf(v);
                        }
                        if (ROWSUM && n0 == 0 && wn == 0 && lr == 0)
                            rsum[(size_t)z * NTOK + m0 + rowLoc] = accr[mt][r];
                    }
                }
            }
            __syncthreads();
            constexpr int ITER = 64 * VPR / 256;
#pragma unroll
            for (int i = 0; i < ITER; i++) {
                const int idx = i * 256 + t;
                const int row = idx / VPR;
                const int cv = idx % VPR;
                short8 val = *(const short8*)&Cs[row * CPITCH + cv * 8];
                *(short8*)&Cout[cz + (size_t)(m0 + c * 64 + row) * ldc + n0 + cv * 8] = val;
            }
            if (c + 1 < BM / 64) __syncthreads();
        }
    } else {
#pragma unroll
        for (int mt = 0; mt < MT; mt++) {
#pragma unroll
            for (int r = 0; r < 4; r++) {
                const int row = m0 + wm + mt * 16 + lq * 4 + r;
                const float bm = BIAS_M ? bias[row] : 0.f;
#pragma unroll
                for (int nt = 0; nt < NT; nt++) {
                    const int col = n0 + wn + nt * 16 + lr;
                    float v = acc[mt][nt][r] * scale + bm;
                    if (BIAS_N) v += bias[col];
                    const size_t idx = cz + (size_t)row * ldc + col;
                    if (ADD_RES) v += res[idx];
                    ((float*)Cv)[idx] = v;
                }
            }
        }
    }
}

// ---------------------------------------------------------------------------
// Split-K reduce: O[row][c] = (P0 + P1) / (RS0[row] + RS1[row]).
// ---------------------------------------------------------------------------
__global__ __launch_bounds__(256)
void pv_reduce(const short* __restrict__ P0, const short* __restrict__ P1,
               const float* __restrict__ RS0, const float* __restrict__ RS1,
               short* __restrict__ O)
{
    const int idx = blockIdx.x * 256 + threadIdx.x;   // short8 units
    const int row = idx >> 6;                         // 64 units per 512-col row
    const float inv = 1.f / (RS0[row] + RS1[row]);
    short8 a = ((const short8*)P0)[idx];
    short8 b = ((const short8*)P1)[idx];
    short8 o;
#pragma unroll
    for (int e = 0; e < 8; e++)
        o[e] = f2bf((bf2f(a[e]) + bf2f(b[e])) * inv);
    ((short8*)O)[idx] = o;
}

// ---------------------------------------------------------------------------
// Launch
// ---------------------------------------------------------------------------
extern "C" void kernel_launch(void* const* d_in, const int* in_sizes, int n_in,
                              void* d_out, int out_size, void* d_ws, size_t ws_size,
                              hipStream_t stream)
{
    (void)in_sizes; (void)n_in; (void)out_size; (void)ws_size;
    const float* x      = (const float*)d_in[0];
    const float* norm_w = (const float*)d_in[1];
    const float* norm_b = (const float*)d_in[2];
    const float* q_w    = (const float*)d_in[3];
    const float* q_b    = (const float*)d_in[4];
    const float* k_w    = (const float*)d_in[5];
    const float* k_b    = (const float*)d_in[6];
    const float* v_w    = (const float*)d_in[7];
    const float* v_b    = (const float*)d_in[8];
    const float* p_w    = (const float*)d_in[9];
    const float* p_b    = (const float*)d_in[10];

    const size_t CN2 = (size_t)NTOK * CH;

    short* hnT = (short*)d_ws;                        // [B][N][C]
    short* QK  = hnT + (size_t)BATCH * CN2;           // [B][N][1024]; later PV partials [2][B][N][C]
    short* V   = QK  + (size_t)BATCH * NTOK * 1024;   // [B][C][N]
    short* O   = V   + (size_t)BATCH * CN2;           // [B][N][C]
    short* wqk = O   + (size_t)BATCH * CN2;           // [1024][512]
    short* wv  = wqk + (size_t)1024 * CH;
    short* wp  = wv  + (size_t)CH * CH;
    short* S   = wp  + (size_t)CH * CH;               // E = exp(scores) [B][N][N] bf16
    float* qkb = (float*)(S + (size_t)BATCH * NTOK * NTOK);   // [1024]
    float2* partials = (float2*)(qkb + 1024);                 // [512]
    float* RS = (float*)(partials + 512);                     // [2*B][N] rowsum partials

    gn_stats_partial<<<dim3(4, BATCH * NGRP), 256, 0, stream>>>(x, partials);
    cast_weights<<<dim3(256, 4), 256, 0, stream>>>(q_w, k_w, v_w, p_w, wqk, wv, wp);
    concat_bias<<<4, 256, 0, stream>>>(q_b, k_b, qkb);
    gn_apply_t<<<dim3(NTOK / 32, CH / 32, BATCH), 256, 0, stream>>>(
        x, norm_w, norm_b, partials, hnT);

    // Fused Q+K conv
    mfma_gemm<128, 128, 64, 2, 1, 0, 1, 0, 0, 0, 0><<<dim3(1024 / 128, NTOK / 128, BATCH), 256, 0, stream>>>(
        hnT, wqk, QK, qkb, nullptr, nullptr, 1.f, CH, CH, CH, 1024,
        (long)CN2, 0, (long)NTOK * 1024);
    // V conv
    mfma_gemm<128, 128, 64, 2, 1, 1, 0, 0, 0, 0, 0><<<dim3(NTOK / 128, CH / 128, BATCH), 256, 0, stream>>>(
        wv, hnT, V, v_b, nullptr, nullptr, 1.f, CH, CH, CH, NTOK,
        0, (long)CN2, (long)CN2);

    const float scale = 1.0f / sqrtf((float)CH);
    // scores -> E = exp(s*scale) bf16. BK=32 + chunked epilogue: ~17KB LDS.
    mfma_gemm<128, 128, 32, 2, 2, 0, 0, 0, 0, 0, 0><<<dim3(NTOK / 128, NTOK / 128, BATCH), 256, 0, stream>>>(
        QK, QK + CH, S, nullptr, nullptr, nullptr, scale, CH, 1024, 1024, NTOK,
        (long)NTOK * 1024, (long)NTOK * 1024, (long)NTOK * NTOK);
    // PV split-K=2, ones-MFMA rowsum partials, bf16 partials over QK buffer
    mfma_gemm<128, 64, 64, 2, 1, 0, 0, 0, 1, 1, 1><<<dim3(NTOK / 128, CH / 64, 8), 256, 0, stream>>>(
        S, V, QK, nullptr, nullptr, RS, 1.f, NTOK / 2, NTOK, NTOK, CH,
        (long)NTOK * NTOK, (long)CN2, (long)CN2);
    // combine partials, divide by combined rowsum -> O bf16
    pv_reduce<<<(BATCH * NTOK * CH / 8) / 256, 256, 0, stream>>>(
        QK, QK + (size_t)BATCH * CN2, RS, RS + (size_t)BATCH * NTOK, O);

    // proj + bias + residual -> out fp32 [b][c][n]
    mfma_gemm<128, 128, 64, 2, 0, 1, 0, 1, 0, 0, 0><<<dim3(NTOK / 128, CH / 128, BATCH), 256, 0, stream>>>(
        wp, O, d_out, p_b, x, nullptr, 1.f, CH, CH, CH, NTOK,
        0, (long)CN2, (long)CN2);
}

// Round 10
// 430.513 us; speedup vs baseline: 1.0403x; 1.0007x over previous
//
#include <hip/hip_runtime.h>
#include <math.h>

#define BATCH 4
#define CH 512
#define NTOK 4096
#define NGRP 32
#define CPG 16
#define GN_EPS 1e-6f

typedef __attribute__((ext_vector_type(8))) short short8;
typedef __attribute__((ext_vector_type(4))) short short4v;
typedef __attribute__((ext_vector_type(4))) float floatx4;

__device__ __forceinline__ short f2bf(float f) {
    unsigned u = __float_as_uint(f);
    u += 0x7fffu + ((u >> 16) & 1u);
    return (short)(u >> 16);
}
__device__ __forceinline__ float bf2f(short s) {
    return __uint_as_float(((unsigned)(unsigned short)s) << 16);
}

__device__ __forceinline__ void load_lds16(const void* g, void* l) {
    __builtin_amdgcn_global_load_lds(
        (const __attribute__((address_space(1))) void*)g,
        (__attribute__((address_space(3))) void*)l,
        16, 0, 0);
}

// ---------------------------------------------------------------------------
// GroupNorm stats, partial: grid (4 parts, 128 bg). partials[bg*4+p]=(sum,ssq)
// ---------------------------------------------------------------------------
__global__ __launch_bounds__(256)
void gn_stats_partial(const float* __restrict__ x, float2* __restrict__ partials)
{
    const int part = blockIdx.x;
    const int bg = blockIdx.y;
    const float4* xp = (const float4*)(x + (size_t)bg * CPG * NTOK) + part * 4096;
    float s = 0.f, ss = 0.f;
    for (int i = threadIdx.x; i < 4096; i += 256) {
        float4 v = xp[i];
        s  += v.x + v.y + v.z + v.w;
        ss += v.x * v.x + v.y * v.y + v.z * v.z + v.w * v.w;
    }
    __shared__ float r0[4], r1[4];
    for (int off = 32; off >= 1; off >>= 1) {
        s  += __shfl_down(s, off);
        ss += __shfl_down(ss, off);
    }
    const int lane = threadIdx.x & 63, wave = threadIdx.x >> 6;
    if (lane == 0) { r0[wave] = s; r1[wave] = ss; }
    __syncthreads();
    if (threadIdx.x == 0) {
        float2 o;
        o.x = r0[0] + r0[1] + r0[2] + r0[3];
        o.y = r1[0] + r1[1] + r1[2] + r1[3];
        partials[bg * 4 + part] = o;
    }
}

// ---------------------------------------------------------------------------
// GroupNorm apply + transpose + bf16. x[b][c][n] -> hnT[b][n][c] bf16.
// ---------------------------------------------------------------------------
__global__ __launch_bounds__(256)
void gn_apply_t(const float* __restrict__ x, const float* __restrict__ gamma,
                const float* __restrict__ beta, const float2* __restrict__ partials,
                short* __restrict__ hnT)
{
    const int b = blockIdx.z;
    const int c0 = blockIdx.y * 32;
    const int n0 = blockIdx.x * 32;
    __shared__ short tile[32][33];
    const int t = threadIdx.x;

    const int cl = t >> 3;
    const int nl = (t & 7) * 4;
    const int c = c0 + cl;
    const int bg = b * NGRP + c / CPG;
    float2 p0 = partials[bg * 4 + 0], p1 = partials[bg * 4 + 1];
    float2 p2 = partials[bg * 4 + 2], p3 = partials[bg * 4 + 3];
    const float inv = 1.f / (float)(CPG * NTOK);
    const float mean = (p0.x + p1.x + p2.x + p3.x) * inv;
    const float var = (p0.y + p1.y + p2.y + p3.y) * inv - mean * mean;
    const float rstd = rsqrtf(var + GN_EPS);
    const float ga = gamma[c] * rstd, be = beta[c] - mean * ga;
    const float4 v = *(const float4*)(x + ((size_t)b * CH + c) * NTOK + n0 + nl);
    tile[cl][nl + 0] = f2bf(v.x * ga + be);
    tile[cl][nl + 1] = f2bf(v.y * ga + be);
    tile[cl][nl + 2] = f2bf(v.z * ga + be);
    tile[cl][nl + 3] = f2bf(v.w * ga + be);
    __syncthreads();

    const int nw = t >> 3;
    const int cw = (t & 7) * 4;
    short4v o;
    o.x = tile[cw + 0][nw];
    o.y = tile[cw + 1][nw];
    o.z = tile[cw + 2][nw];
    o.w = tile[cw + 3][nw];
    *(short4v*)(hnT + ((size_t)b * NTOK + n0 + nw) * CH + c0 + cw) = o;
}

// ---------------------------------------------------------------------------
// Weight casts. Grid (256, 4).
// ---------------------------------------------------------------------------
__global__ __launch_bounds__(256)
void cast_weights(const float* q, const float* k, const float* v, const float* p,
                  short* wqk, short* wv, short* wp)
{
    const float* w; short* o;
    switch (blockIdx.y) {
        case 0: w = q; o = wqk; break;
        case 1: w = k; o = wqk + CH * CH; break;
        case 2: w = v; o = wv; break;
        default: w = p; o = wp; break;
    }
    const int i = blockIdx.x * 256 + threadIdx.x;
    const float4 vv = ((const float4*)w)[i];
    short4v s; s.x = f2bf(vv.x); s.y = f2bf(vv.y); s.z = f2bf(vv.z); s.w = f2bf(vv.w);
    ((short4v*)o)[i] = s;
}

__global__ __launch_bounds__(256)
void concat_bias(const float* q_b, const float* k_b, float* qkb)
{
    const int i = blockIdx.x * 256 + threadIdx.x;
    qkb[i] = (i < CH) ? q_b[i] : k_b[i - CH];
}

// ---------------------------------------------------------------------------
// bf16 MFMA GEMM (TN): C[m][n] = scale*sum_k A[m][k]*B[n][k] (+bias)(+res)
// MODE: 0 = fp32 out (direct store), 1 = bf16 out, 2 = bf16 exp(out)
// MODE>=1: chunked LDS-staged epilogue (64 rows at a time, coalesced stores).
// SPLITK: z encodes (split=z>>2, batch=z&3); k-range offset split*K.
// ---------------------------------------------------------------------------
template<int BM, int BN, int BK, int WAVES_M, int MODE, int BIAS_M,
         int BIAS_N, int ADD_RES, int SWAP_XY, int SPLITK>
__global__ __launch_bounds__(256)
void mfma_gemm(const short* __restrict__ A, const short* __restrict__ B,
               void* __restrict__ Cv, const float* __restrict__ bias,
               const float* __restrict__ res, float scale,
               int K, int lda, int ldb, int ldc,
               long sA, long sB, long sC)
{
    constexpr int WAVES_N = 4 / WAVES_M;
    constexpr int WM = BM / WAVES_M;
    constexpr int WN = BN / WAVES_N;
    constexpr int MT = WM / 16;
    constexpr int NT = WN / 16;
    constexpr int KS = BK / 32;
    constexpr int TPR = BK / 8;
    constexpr int RPI = 256 / TPR;
    constexpr int CPITCH = BN + 8;
    constexpr int STAGE = BM * BK + BN * BK;
    constexpr int EPI = (MODE >= 1) ? 64 * CPITCH : 0;
    constexpr int LDSE = STAGE > EPI ? STAGE : EPI;

    __shared__ __align__(16) short lds[LDSE];
    short* As = lds;
    short* Bs = lds + BM * BK;

    const int z = blockIdx.z;
    const int zb = SPLITK ? (z & 3) : z;
    const int koff = SPLITK ? (z >> 2) * K : 0;
    const short* Ap = A + (size_t)zb * sA + koff;
    const short* Bp = B + (size_t)zb * sB + koff;

    const int m0 = (SWAP_XY ? blockIdx.x : blockIdx.y) * BM;
    const int n0 = (SWAP_XY ? blockIdx.y : blockIdx.x) * BN;
    const int t = threadIdx.x;
    const int w = t >> 6, lane = t & 63;
    const int wm = (w % WAVES_M) * WM;
    const int wn = (w / WAVES_M) * WN;
    const int lr = lane & 15, lq = lane >> 4;

    floatx4 acc[MT][NT];
#pragma unroll
    for (int mt = 0; mt < MT; mt++)
#pragma unroll
        for (int nt = 0; nt < NT; nt++)
            acc[mt][nt] = (floatx4){0.f, 0.f, 0.f, 0.f};

    const int rA = t / TPR;
    const int kA = (t % TPR) * 8;

    for (int k0 = 0; k0 < K; k0 += BK) {
#pragma unroll
        for (int r = 0; r < BM; r += RPI)
            load_lds16(Ap + (size_t)(m0 + r + rA) * lda + k0 + kA,
                       &As[(r + rA) * BK + kA]);
#pragma unroll
        for (int r = 0; r < BN; r += RPI)
            load_lds16(Bp + (size_t)(n0 + r + rA) * ldb + k0 + kA,
                       &Bs[(r + rA) * BK + kA]);
        __syncthreads();

#pragma unroll
        for (int ks = 0; ks < KS; ks++) {
            short8 af[MT], bfr[NT];
#pragma unroll
            for (int mt = 0; mt < MT; mt++)
                af[mt] = *(const short8*)&As[(wm + mt * 16 + lr) * BK + ks * 32 + lq * 8];
#pragma unroll
            for (int nt = 0; nt < NT; nt++)
                bfr[nt] = *(const short8*)&Bs[(wn + nt * 16 + lr) * BK + ks * 32 + lq * 8];
#pragma unroll
            for (int mt = 0; mt < MT; mt++)
#pragma unroll
                for (int nt = 0; nt < NT; nt++)
                    acc[mt][nt] = __builtin_amdgcn_mfma_f32_16x16x32_bf16(
                        af[mt], bfr[nt], acc[mt][nt], 0, 0, 0);
        }
        __syncthreads();
    }

    // C/D: col = lane&15, row = (lane>>4)*4 + r  [m89-verified]
    const size_t cz = (size_t)z * sC;
    if (MODE >= 1) {
        short* Cs = lds;
        short* Cout = (short*)Cv;
        constexpr int VPR = BN / 8;
#pragma unroll
        for (int c = 0; c < BM / 64; c++) {
            if (wm == c * 64) {
#pragma unroll
                for (int mt = 0; mt < MT; mt++) {
#pragma unroll
                    for (int r = 0; r < 4; r++) {
                        const int rowLoc = wm + mt * 16 + lq * 4 + r;
                        const int rowCs = rowLoc - c * 64;
                        const float bm = BIAS_M ? bias[m0 + rowLoc] : 0.f;
#pragma unroll
                        for (int nt = 0; nt < NT; nt++) {
                            const int colLoc = wn + nt * 16 + lr;
                            float v = acc[mt][nt][r] * scale + bm;
                            if (BIAS_N) v += bias[n0 + colLoc];
                            if (MODE == 2) v = __expf(v);
                            Cs[rowCs * CPITCH + colLoc] = f2bf(v);
                        }
                    }
                }
            }
            __syncthreads();
            constexpr int ITER = 64 * VPR / 256;
#pragma unroll
            for (int i = 0; i < ITER; i++) {
                const int idx = i * 256 + t;
                const int row = idx / VPR;
                const int cv = idx % VPR;
                short8 val = *(const short8*)&Cs[row * CPITCH + cv * 8];
                *(short8*)&Cout[cz + (size_t)(m0 + c * 64 + row) * ldc + n0 + cv * 8] = val;
            }
            if (c + 1 < BM / 64) __syncthreads();
        }
    } else {
#pragma unroll
        for (int mt = 0; mt < MT; mt++) {
#pragma unroll
            for (int r = 0; r < 4; r++) {
                const int row = m0 + wm + mt * 16 + lq * 4 + r;
                const float bm = BIAS_M ? bias[row] : 0.f;
#pragma unroll
                for (int nt = 0; nt < NT; nt++) {
                    const int col = n0 + wn + nt * 16 + lr;
                    float v = acc[mt][nt][r] * scale + bm;
                    if (BIAS_N) v += bias[col];
                    const size_t idx = cz + (size_t)row * ldc + col;
                    if (ADD_RES) v += res[idx];
                    ((float*)Cv)[idx] = v;
                }
            }
        }
    }
}

// ---------------------------------------------------------------------------
// Row sums of E: RS[row] = sum_j E[row][j].  One wave per row, 4096 blocks.
// ---------------------------------------------------------------------------
__global__ __launch_bounds__(256)
void row_sums(const short* __restrict__ E, float* __restrict__ RS)
{
    const int wave = threadIdx.x >> 6, lane = threadIdx.x & 63;
    const int row = blockIdx.x * 4 + wave;
    const short8* rp = (const short8*)(E + (size_t)row * NTOK);   // 512 units
    float s = 0.f;
#pragma unroll
    for (int i = 0; i < 8; i++) {
        short8 v = rp[i * 64 + lane];
#pragma unroll
        for (int e = 0; e < 8; e++) s += bf2f(v[e]);
    }
    for (int off = 32; off >= 1; off >>= 1) s += __shfl_down(s, off);
    if (lane == 0) RS[row] = s;
}

// ---------------------------------------------------------------------------
// Split-K reduce: O[row][c] = (P0 + P1) / RS[row].
// ---------------------------------------------------------------------------
__global__ __launch_bounds__(256)
void pv_reduce(const short* __restrict__ P0, const short* __restrict__ P1,
               const float* __restrict__ RS, short* __restrict__ O)
{
    const int idx = blockIdx.x * 256 + threadIdx.x;   // short8 units
    const int row = idx >> 6;                         // 64 units per 512-col row
    const float inv = 1.f / RS[row];
    short8 a = ((const short8*)P0)[idx];
    short8 b = ((const short8*)P1)[idx];
    short8 o;
#pragma unroll
    for (int e = 0; e < 8; e++)
        o[e] = f2bf((bf2f(a[e]) + bf2f(b[e])) * inv);
    ((short8*)O)[idx] = o;
}

// ---------------------------------------------------------------------------
// Launch
// ---------------------------------------------------------------------------
extern "C" void kernel_launch(void* const* d_in, const int* in_sizes, int n_in,
                              void* d_out, int out_size, void* d_ws, size_t ws_size,
                              hipStream_t stream)
{
    (void)in_sizes; (void)n_in; (void)out_size; (void)ws_size;
    const float* x      = (const float*)d_in[0];
    const float* norm_w = (const float*)d_in[1];
    const float* norm_b = (const float*)d_in[2];
    const float* q_w    = (const float*)d_in[3];
    const float* q_b    = (const float*)d_in[4];
    const float* k_w    = (const float*)d_in[5];
    const float* k_b    = (const float*)d_in[6];
    const float* v_w    = (const float*)d_in[7];
    const float* v_b    = (const float*)d_in[8];
    const float* p_w    = (const float*)d_in[9];
    const float* p_b    = (const float*)d_in[10];

    const size_t CN2 = (size_t)NTOK * CH;

    short* hnT = (short*)d_ws;                        // [B][N][C]
    short* QK  = hnT + (size_t)BATCH * CN2;           // [B][N][1024]; later PV partials [2][B][N][C]
    short* V   = QK  + (size_t)BATCH * NTOK * 1024;   // [B][C][N]
    short* O   = V   + (size_t)BATCH * CN2;           // [B][N][C]
    short* wqk = O   + (size_t)BATCH * CN2;           // [1024][512]
    short* wv  = wqk + (size_t)1024 * CH;
    short* wp  = wv  + (size_t)CH * CH;
    short* S   = wp  + (size_t)CH * CH;               // E = exp(scores) [B][N][N] bf16
    float* qkb = (float*)(S + (size_t)BATCH * NTOK * NTOK);   // [1024]
    float2* partials = (float2*)(qkb + 1024);                 // [512]
    float* RS = (float*)(partials + 512);                     // [B][N] rowsums

    gn_stats_partial<<<dim3(4, BATCH * NGRP), 256, 0, stream>>>(x, partials);
    cast_weights<<<dim3(256, 4), 256, 0, stream>>>(q_w, k_w, v_w, p_w, wqk, wv, wp);
    concat_bias<<<4, 256, 0, stream>>>(q_b, k_b, qkb);
    gn_apply_t<<<dim3(NTOK / 32, CH / 32, BATCH), 256, 0, stream>>>(
        x, norm_w, norm_b, partials, hnT);

    // Fused Q+K conv
    mfma_gemm<128, 128, 64, 2, 1, 0, 1, 0, 0, 0><<<dim3(1024 / 128, NTOK / 128, BATCH), 256, 0, stream>>>(
        hnT, wqk, QK, qkb, nullptr, 1.f, CH, CH, CH, 1024,
        (long)CN2, 0, (long)NTOK * 1024);
    // V conv
    mfma_gemm<128, 128, 64, 2, 1, 1, 0, 0, 0, 0><<<dim3(NTOK / 128, CH / 128, BATCH), 256, 0, stream>>>(
        wv, hnT, V, v_b, nullptr, 1.f, CH, CH, CH, NTOK,
        0, (long)CN2, (long)CN2);

    const float scale = 1.0f / sqrtf((float)CH);
    // scores -> E = exp(s*scale) bf16. BK=32 + chunked epilogue.
    mfma_gemm<128, 128, 32, 2, 2, 0, 0, 0, 0, 0><<<dim3(NTOK / 128, NTOK / 128, BATCH), 256, 0, stream>>>(
        QK, QK + CH, S, nullptr, nullptr, scale, CH, 1024, 1024, NTOK,
        (long)NTOK * 1024, (long)NTOK * 1024, (long)NTOK * NTOK);
    // exact row sums of E (replaces ones-MFMA / epilogue atomics)
    row_sums<<<BATCH * NTOK / 4, 256, 0, stream>>>(S, RS);
    // PV split-K=2, pure MFMA inner loop, bf16 partials over QK buffer
    mfma_gemm<128, 64, 64, 2, 1, 0, 0, 0, 1, 1><<<dim3(NTOK / 128, CH / 64, 8), 256, 0, stream>>>(
        S, V, QK, nullptr, nullptr, 1.f, NTOK / 2, NTOK, NTOK, CH,
        (long)NTOK * NTOK, (long)CN2, (long)CN2);
    // combine partials, divide by rowsum -> O bf16
    pv_reduce<<<(BATCH * NTOK * CH / 8) / 256, 256, 0, stream>>>(
        QK, QK + (size_t)BATCH * CN2, RS, O);

    // proj + bias + residual -> out fp32 [b][c][n]
    mfma_gemm<128, 128, 64, 2, 0, 1, 0, 1, 0, 0><<<dim3(NTOK / 128, CH / 128, BATCH), 256, 0, stream>>>(
        wp, O, d_out, p_b, x, 1.f, CH, CH, CH, NTOK,
        0, (long)CN2, (long)CN2);
}